// Round 1
// baseline (5437.431 us; speedup 1.0000x reference)
//
#include <hip/hip_runtime.h>
#include <hip/hip_bf16.h>
#include <math.h>

#define N_NODES 100000
#define N_EDGES 1600000
#define IN_C    500
#define HID     256
#define OUT_C   40
#define K_ITERS 10
#define ALPHA   0.1f
#define LN_EPS  1e-5f

// ---------------------------------------------------------------------------
// degree / norm precompute
// ---------------------------------------------------------------------------
__global__ void deg_init_kernel(float* __restrict__ deg, int n) {
    int i = blockIdx.x * blockDim.x + threadIdx.x;
    if (i < n) deg[i] = 1.0f;  // self-loop contribution
}

__global__ void deg_count_kernel(const int* __restrict__ col, float* __restrict__ deg, int e) {
    int i = blockIdx.x * blockDim.x + threadIdx.x;
    if (i < e) atomicAdd(&deg[col[i]], 1.0f);
}

__global__ void deg_to_dinv_kernel(float* __restrict__ deg, int n) {
    int i = blockIdx.x * blockDim.x + threadIdx.x;
    if (i < n) deg[i] = rsqrtf(deg[i]);  // deg >= 1 always (self loops)
}

__global__ void norm_kernel(const int* __restrict__ row, const int* __restrict__ col,
                            const float* __restrict__ dinv, float* __restrict__ nrm, int e) {
    int i = blockIdx.x * blockDim.x + threadIdx.x;
    if (i < e) nrm[i] = dinv[row[i]] * dinv[col[i]];
}

// ---------------------------------------------------------------------------
// tiled fp32 GEMM: C[M,N] = A[M,K] @ B[K,N] + bias, optional exact GELU
// 64x64 tile, BK=16, 256 threads, 4x4 per thread
// ---------------------------------------------------------------------------
#define BM 64
#define BN 64
#define BK 16

__global__ __launch_bounds__(256) void gemm_bias_gelu_kernel(
    const float* __restrict__ A, const float* __restrict__ B,
    const float* __restrict__ bias, float* __restrict__ C,
    int M, int N, int K, int do_gelu)
{
    __shared__ __align__(16) float As[BK][BM + 4];  // stride 68: 16B-aligned rows, 2-way-max banks
    __shared__ __align__(16) float Bs[BK][BN];

    const int tid = threadIdx.x;
    const int tx  = tid & 15;   // col group 0..15
    const int ty  = tid >> 4;   // row group 0..15
    const int row0 = blockIdx.y * BM;
    const int col0 = blockIdx.x * BN;

    const int a_k = tid & 15;   // k within tile
    const int a_r = tid >> 4;   // row 0..15 (+16 x4)
    const int b_c = tid & 63;
    const int b_k = tid >> 6;   // 0..3 (+4 x4)

    float acc[4][4] = {};

    for (int k0 = 0; k0 < K; k0 += BK) {
        #pragma unroll
        for (int i = 0; i < 4; i++) {
            int r = a_r + 16 * i;
            int gr = row0 + r, gk = k0 + a_k;
            float v = 0.0f;
            if (gr < M && gk < K) v = A[(size_t)gr * K + gk];
            As[a_k][r] = v;
        }
        #pragma unroll
        for (int i = 0; i < 4; i++) {
            int kk = b_k + 4 * i;
            int gk = k0 + kk;
            float v = 0.0f;
            if (gk < K) v = B[(size_t)gk * N + col0 + b_c];
            Bs[kk][b_c] = v;
        }
        __syncthreads();
        #pragma unroll
        for (int kk = 0; kk < BK; kk++) {
            const float4 av = *reinterpret_cast<const float4*>(&As[kk][ty * 4]);
            const float4 bv = *reinterpret_cast<const float4*>(&Bs[kk][tx * 4]);
            const float a[4] = {av.x, av.y, av.z, av.w};
            const float b[4] = {bv.x, bv.y, bv.z, bv.w};
            #pragma unroll
            for (int i = 0; i < 4; i++)
                #pragma unroll
                for (int j = 0; j < 4; j++)
                    acc[i][j] += a[i] * b[j];
        }
        __syncthreads();
    }

    #pragma unroll
    for (int i = 0; i < 4; i++) {
        int gr = row0 + ty * 4 + i;
        if (gr >= M) continue;
        #pragma unroll
        for (int j = 0; j < 4; j++) {
            int gc = col0 + tx * 4 + j;
            float v = acc[i][j] + bias[gc];
            if (do_gelu) v = 0.5f * v * (1.0f + erff(v * 0.70710678118654752f));
            C[(size_t)gr * N + gc] = v;
        }
    }
}

// ---------------------------------------------------------------------------
// LayerNorm over last dim (256), in place. One wave per row, 4 rows/block.
// ---------------------------------------------------------------------------
__global__ __launch_bounds__(256) void layernorm_kernel(
    float* __restrict__ h, const float* __restrict__ g, const float* __restrict__ b, int nrows)
{
    const int wave = threadIdx.x >> 6;
    const int lane = threadIdx.x & 63;
    const int row  = blockIdx.x * 4 + wave;
    if (row >= nrows) return;

    float* p = h + (size_t)row * HID;
    float v[4];
    float s = 0.0f;
    #pragma unroll
    for (int j = 0; j < 4; j++) { v[j] = p[lane + 64 * j]; s += v[j]; }
    #pragma unroll
    for (int off = 32; off > 0; off >>= 1) s += __shfl_xor(s, off);
    const float mu = s * (1.0f / 256.0f);

    float vs = 0.0f;
    #pragma unroll
    for (int j = 0; j < 4; j++) { float d = v[j] - mu; vs += d * d; }
    #pragma unroll
    for (int off = 32; off > 0; off >>= 1) vs += __shfl_xor(vs, off);
    const float rs = rsqrtf(vs * (1.0f / 256.0f) + LN_EPS);

    #pragma unroll
    for (int j = 0; j < 4; j++) {
        int c = lane + 64 * j;
        p[c] = (v[j] - mu) * rs * g[c] + b[c];
    }
}

// ---------------------------------------------------------------------------
// GEMM3: [N,256] @ [256,40] + b3, W3 staged in LDS (40 KB)
// ---------------------------------------------------------------------------
__global__ __launch_bounds__(256) void gemm3_kernel(
    const float* __restrict__ A, const float* __restrict__ W,
    const float* __restrict__ bias, float* __restrict__ C, int M)
{
    __shared__ float Ws[HID * OUT_C];
    __shared__ float bs[OUT_C];
    for (int i = threadIdx.x; i < HID * OUT_C; i += 256) Ws[i] = W[i];
    if (threadIdx.x < OUT_C) bs[threadIdx.x] = bias[threadIdx.x];
    __syncthreads();

    const int total = M * OUT_C;
    for (int idx = blockIdx.x * 256 + threadIdx.x; idx < total; idx += gridDim.x * 256) {
        const int r = idx / OUT_C;
        const int c = idx - r * OUT_C;
        const float4* a4 = reinterpret_cast<const float4*>(A + (size_t)r * HID);
        float s = 0.0f;
        #pragma unroll 4
        for (int k4 = 0; k4 < HID / 4; k4++) {
            float4 av = a4[k4];
            const float* wp = &Ws[k4 * 4 * OUT_C + c];
            s += av.x * wp[0] + av.y * wp[OUT_C] + av.z * wp[2 * OUT_C] + av.w * wp[3 * OUT_C];
        }
        C[idx] = s + bs[c];
    }
}

// ---------------------------------------------------------------------------
// APPNP scatter: 8 lanes per edge, 5 channels per lane, atomic add into agg
// ---------------------------------------------------------------------------
__global__ __launch_bounds__(256) void scatter_kernel(
    const int* __restrict__ row, const int* __restrict__ col,
    const float* __restrict__ nrm, const float* __restrict__ h,
    float* __restrict__ agg, int e)
{
    const int t = blockIdx.x * 256 + threadIdx.x;
    const int ed = t >> 3;
    if (ed >= e) return;
    const int c = t & 7;
    const int r  = row[ed];
    const int cl = col[ed];
    const float nm = nrm[ed];
    const float* hp = h + (size_t)r * OUT_C + c;
    float* ap = agg + (size_t)cl * OUT_C + c;
    #pragma unroll
    for (int j = 0; j < 5; j++) atomicAdd(ap + 8 * j, nm * hp[8 * j]);
}

// combine: out = (1-a)*(agg + dinv[i]^2 * h) + a*h0    (float4 over 40 = 10x float4)
__global__ __launch_bounds__(256) void combine_kernel(
    const float* __restrict__ agg, const float* __restrict__ h,
    const float* __restrict__ h0, const float* __restrict__ dinv,
    float* __restrict__ out, int n)
{
    const int total4 = n * (OUT_C / 4);
    int idx = blockIdx.x * 256 + threadIdx.x;
    if (idx >= total4) return;
    const int r = idx / (OUT_C / 4);
    const float d = dinv[r];
    const float self = d * d;
    const float4 ag = reinterpret_cast<const float4*>(agg)[idx];
    const float4 hv = reinterpret_cast<const float4*>(h)[idx];
    const float4 h0v = reinterpret_cast<const float4*>(h0)[idx];
    float4 o;
    o.x = (1.0f - ALPHA) * (ag.x + self * hv.x) + ALPHA * h0v.x;
    o.y = (1.0f - ALPHA) * (ag.y + self * hv.y) + ALPHA * h0v.y;
    o.z = (1.0f - ALPHA) * (ag.z + self * hv.z) + ALPHA * h0v.z;
    o.w = (1.0f - ALPHA) * (ag.w + self * hv.w) + ALPHA * h0v.w;
    reinterpret_cast<float4*>(out)[idx] = o;
}

// ---------------------------------------------------------------------------
extern "C" void kernel_launch(void* const* d_in, const int* in_sizes, int n_in,
                              void* d_out, int out_size, void* d_ws, size_t ws_size,
                              hipStream_t stream) {
    const float* x   = (const float*)d_in[0];
    const int*   ei  = (const int*)d_in[1];     // [2, E] int32
    const float* W1  = (const float*)d_in[2];
    const float* b1  = (const float*)d_in[3];
    const float* g1  = (const float*)d_in[4];
    const float* be1 = (const float*)d_in[5];
    const float* W2  = (const float*)d_in[6];
    const float* b2  = (const float*)d_in[7];
    const float* g2  = (const float*)d_in[8];
    const float* be2 = (const float*)d_in[9];
    const float* W3  = (const float*)d_in[10];
    const float* b3  = (const float*)d_in[11];
    float* out = (float*)d_out;

    const int* e_row = ei;
    const int* e_col = ei + N_EDGES;

    // workspace layout (floats): dinv[N] | norm[E] | t1[N*256] | t2[N*256]
    // h0/hA/hB/agg alias into t1 (dead after GEMM2): 4 * N*40 = N*160 < N*256
    float* ws   = (float*)d_ws;
    float* dinv = ws;
    float* nrm  = ws + N_NODES;
    float* t1   = nrm + N_EDGES;
    float* t2   = t1 + (size_t)N_NODES * HID;
    float* h0   = t1;
    float* hA   = t1 + (size_t)N_NODES * OUT_C;
    float* hB   = t1 + (size_t)N_NODES * OUT_C * 2;
    float* agg  = t1 + (size_t)N_NODES * OUT_C * 3;

    // --- GCN norm precompute ---
    deg_init_kernel<<<(N_NODES + 255) / 256, 256, 0, stream>>>(dinv, N_NODES);
    deg_count_kernel<<<(N_EDGES + 255) / 256, 256, 0, stream>>>(e_col, dinv, N_EDGES);
    deg_to_dinv_kernel<<<(N_NODES + 255) / 256, 256, 0, stream>>>(dinv, N_NODES);
    norm_kernel<<<(N_EDGES + 255) / 256, 256, 0, stream>>>(e_row, e_col, dinv, nrm, N_EDGES);

    // --- MLP ---
    {
        dim3 grid(HID / BN, (N_NODES + BM - 1) / BM);
        gemm_bias_gelu_kernel<<<grid, 256, 0, stream>>>(x, W1, b1, t1, N_NODES, HID, IN_C, 1);
        layernorm_kernel<<<(N_NODES + 3) / 4, 256, 0, stream>>>(t1, g1, be1, N_NODES);
        gemm_bias_gelu_kernel<<<grid, 256, 0, stream>>>(t1, W2, b2, t2, N_NODES, HID, HID, 1);
        layernorm_kernel<<<(N_NODES + 3) / 4, 256, 0, stream>>>(t2, g2, be2, N_NODES);
        gemm3_kernel<<<2048, 256, 0, stream>>>(t2, W3, b3, h0, N_NODES);
    }

    // --- APPNP: 10 propagation steps ---
    const float* hcur = h0;
    const size_t hbytes = (size_t)N_NODES * OUT_C * sizeof(float);
    for (int it = 0; it < K_ITERS; it++) {
        float* tgt = (it == K_ITERS - 1) ? out : ((it & 1) ? hB : hA);
        hipMemsetAsync(agg, 0, hbytes, stream);
        scatter_kernel<<<(N_EDGES * 8 + 255) / 256, 256, 0, stream>>>(e_row, e_col, nrm, hcur, agg, N_EDGES);
        combine_kernel<<<(N_NODES * (OUT_C / 4) + 255) / 256, 256, 0, stream>>>(agg, hcur, h0, dinv, tgt, N_NODES);
        hcur = tgt;
    }
}

// Round 2
// 2435.669 us; speedup vs baseline: 2.2324x; 2.2324x over previous
//
#include <hip/hip_runtime.h>
#include <hip/hip_bf16.h>
#include <math.h>

#define N_NODES 100000
#define N_EDGES 1600000
#define IN_C    500
#define HID     256
#define OUT_C   40
#define K_ITERS 10
#define ALPHA   0.1f
#define LN_EPS  1e-5f

#define SCAN_CHUNK 1024
#define NBLK_SCAN  ((N_NODES + SCAN_CHUNK - 1) / SCAN_CHUNK)   // 98

// ---------------------------------------------------------------------------
// degree count (in-degree of edges, excluding self-loop)
// ---------------------------------------------------------------------------
__global__ void deg_count_kernel(const int* __restrict__ col, int* __restrict__ cnt, int e) {
    int i = blockIdx.x * blockDim.x + threadIdx.x;
    if (i < e) atomicAdd(&cnt[col[i]], 1);
}

__global__ void dinv_kernel(const int* __restrict__ cnt, float* __restrict__ dinv, int n) {
    int i = blockIdx.x * blockDim.x + threadIdx.x;
    if (i < n) dinv[i] = rsqrtf((float)cnt[i] + 1.0f);  // +1 = self loop
}

// ---------------------------------------------------------------------------
// 3-kernel exclusive scan of cnt[N] -> offs[N] (+ offs[N]=E)
// ---------------------------------------------------------------------------
__global__ __launch_bounds__(256) void scan_partial_kernel(const int* __restrict__ cnt,
                                                           int* __restrict__ bsum) {
    __shared__ int s[256];
    const int base = blockIdx.x * SCAN_CHUNK;
    const int t = threadIdx.x;
    int sum = 0;
    #pragma unroll
    for (int j = 0; j < 4; j++) {
        int idx = base + t * 4 + j;
        if (idx < N_NODES) sum += cnt[idx];
    }
    s[t] = sum;
    __syncthreads();
    for (int off = 128; off > 0; off >>= 1) {
        if (t < off) s[t] += s[t + off];
        __syncthreads();
    }
    if (t == 0) bsum[blockIdx.x] = s[0];
}

__global__ __launch_bounds__(128) void scan_bsum_kernel(int* __restrict__ bsum, int nblk) {
    __shared__ int s[128];
    const int t = threadIdx.x;
    const int orig = (t < nblk) ? bsum[t] : 0;
    s[t] = orig;
    __syncthreads();
    for (int off = 1; off < 128; off <<= 1) {
        int v = 0;
        if (t >= off) v = s[t - off];
        __syncthreads();
        s[t] += v;
        __syncthreads();
    }
    if (t < nblk) bsum[t] = s[t] - orig;   // exclusive
}

__global__ __launch_bounds__(256) void scan_final_kernel(const int* __restrict__ cnt,
                                                         const int* __restrict__ bsum,
                                                         int* __restrict__ offs) {
    __shared__ int s[256];
    const int base = blockIdx.x * SCAN_CHUNK;
    const int t = threadIdx.x;
    int v[4];
    int lsum = 0;
    #pragma unroll
    for (int j = 0; j < 4; j++) {
        int idx = base + t * 4 + j;
        v[j] = (idx < N_NODES) ? cnt[idx] : 0;
        lsum += v[j];
    }
    s[t] = lsum;
    __syncthreads();
    const int orig = lsum;
    for (int off = 1; off < 256; off <<= 1) {
        int u = 0;
        if (t >= off) u = s[t - off];
        __syncthreads();
        s[t] += u;
        __syncthreads();
    }
    int run = bsum[blockIdx.x] + (s[t] - orig);
    #pragma unroll
    for (int j = 0; j < 4; j++) {
        int idx = base + t * 4 + j;
        if (idx < N_NODES) offs[idx] = run;
        run += v[j];
    }
}

__global__ void set_total_kernel(int* __restrict__ offs) {
    if (threadIdx.x == 0 && blockIdx.x == 0) offs[N_NODES] = N_EDGES;
}

// ---------------------------------------------------------------------------
// CSR fill: group edges by target col; weight = dinv[row]*dinv[col]
// ---------------------------------------------------------------------------
__global__ void csr_fill_kernel(const int* __restrict__ row, const int* __restrict__ col,
                                const float* __restrict__ dinv, const int* __restrict__ offs,
                                int* __restrict__ cursor, int* __restrict__ csr_src,
                                float* __restrict__ csr_w, int e) {
    int i = blockIdx.x * blockDim.x + threadIdx.x;
    if (i >= e) return;
    const int r = row[i], c = col[i];
    const int p = offs[c] + atomicAdd(&cursor[c], 1);
    csr_src[p] = r;
    csr_w[p]   = dinv[r] * dinv[c];
}

// ---------------------------------------------------------------------------
// tiled fp32 GEMM: C[M,N] = A[M,K] @ B[K,N] + bias, optional exact GELU
// ---------------------------------------------------------------------------
#define BM 64
#define BN 64
#define BK 16

__global__ __launch_bounds__(256) void gemm_bias_gelu_kernel(
    const float* __restrict__ A, const float* __restrict__ B,
    const float* __restrict__ bias, float* __restrict__ C,
    int M, int N, int K, int do_gelu)
{
    __shared__ __align__(16) float As[BK][BM + 4];
    __shared__ __align__(16) float Bs[BK][BN + 4];

    const int tid = threadIdx.x;
    const int tx  = tid & 15;
    const int ty  = tid >> 4;
    const int row0 = blockIdx.y * BM;
    const int col0 = blockIdx.x * BN;

    const int a_k = tid & 15;
    const int a_r = tid >> 4;
    const int b_c = tid & 63;
    const int b_k = tid >> 6;

    float acc[4][4] = {};

    for (int k0 = 0; k0 < K; k0 += BK) {
        #pragma unroll
        for (int i = 0; i < 4; i++) {
            int r = a_r + 16 * i;
            int gr = row0 + r, gk = k0 + a_k;
            float v = 0.0f;
            if (gr < M && gk < K) v = A[(size_t)gr * K + gk];
            As[a_k][r] = v;
        }
        #pragma unroll
        for (int i = 0; i < 4; i++) {
            int kk = b_k + 4 * i;
            int gk = k0 + kk;
            float v = 0.0f;
            if (gk < K) v = B[(size_t)gk * N + col0 + b_c];
            Bs[kk][b_c] = v;
        }
        __syncthreads();
        #pragma unroll
        for (int kk = 0; kk < BK; kk++) {
            const float4 av = *reinterpret_cast<const float4*>(&As[kk][ty * 4]);
            const float4 bv = *reinterpret_cast<const float4*>(&Bs[kk][tx * 4]);
            const float a[4] = {av.x, av.y, av.z, av.w};
            const float b[4] = {bv.x, bv.y, bv.z, bv.w};
            #pragma unroll
            for (int i = 0; i < 4; i++)
                #pragma unroll
                for (int j = 0; j < 4; j++)
                    acc[i][j] += a[i] * b[j];
        }
        __syncthreads();
    }

    #pragma unroll
    for (int i = 0; i < 4; i++) {
        int gr = row0 + ty * 4 + i;
        if (gr >= M) continue;
        #pragma unroll
        for (int j = 0; j < 4; j++) {
            int gc = col0 + tx * 4 + j;
            float v = acc[i][j] + bias[gc];
            if (do_gelu) v = 0.5f * v * (1.0f + erff(v * 0.70710678118654752f));
            C[(size_t)gr * N + gc] = v;
        }
    }
}

// ---------------------------------------------------------------------------
// LayerNorm over last dim (256), in place. One wave per row, 4 rows/block.
// ---------------------------------------------------------------------------
__global__ __launch_bounds__(256) void layernorm_kernel(
    float* __restrict__ h, const float* __restrict__ g, const float* __restrict__ b, int nrows)
{
    const int wave = threadIdx.x >> 6;
    const int lane = threadIdx.x & 63;
    const int row  = blockIdx.x * 4 + wave;
    if (row >= nrows) return;

    float* p = h + (size_t)row * HID;
    float v[4];
    float s = 0.0f;
    #pragma unroll
    for (int j = 0; j < 4; j++) { v[j] = p[lane + 64 * j]; s += v[j]; }
    #pragma unroll
    for (int off = 32; off > 0; off >>= 1) s += __shfl_xor(s, off);
    const float mu = s * (1.0f / 256.0f);

    float vs = 0.0f;
    #pragma unroll
    for (int j = 0; j < 4; j++) { float d = v[j] - mu; vs += d * d; }
    #pragma unroll
    for (int off = 32; off > 0; off >>= 1) vs += __shfl_xor(vs, off);
    const float rs = rsqrtf(vs * (1.0f / 256.0f) + LN_EPS);

    #pragma unroll
    for (int j = 0; j < 4; j++) {
        int c = lane + 64 * j;
        p[c] = (v[j] - mu) * rs * g[c] + b[c];
    }
}

// ---------------------------------------------------------------------------
// GEMM3: [N,256] @ [256,40] + b3, W3 staged in LDS (40 KB)
// ---------------------------------------------------------------------------
__global__ __launch_bounds__(256) void gemm3_kernel(
    const float* __restrict__ A, const float* __restrict__ W,
    const float* __restrict__ bias, float* __restrict__ C, int M)
{
    __shared__ float Ws[HID * OUT_C];
    __shared__ float bs[OUT_C];
    for (int i = threadIdx.x; i < HID * OUT_C; i += 256) Ws[i] = W[i];
    if (threadIdx.x < OUT_C) bs[threadIdx.x] = bias[threadIdx.x];
    __syncthreads();

    const int total = M * OUT_C;
    for (int idx = blockIdx.x * 256 + threadIdx.x; idx < total; idx += gridDim.x * 256) {
        const int r = idx / OUT_C;
        const int c = idx - r * OUT_C;
        const float4* a4 = reinterpret_cast<const float4*>(A + (size_t)r * HID);
        float s = 0.0f;
        #pragma unroll 4
        for (int k4 = 0; k4 < HID / 4; k4++) {
            float4 av = a4[k4];
            const float* wp = &Ws[k4 * 4 * OUT_C + c];
            s += av.x * wp[0] + av.y * wp[OUT_C] + av.z * wp[2 * OUT_C] + av.w * wp[3 * OUT_C];
        }
        C[idx] = s + bs[c];
    }
}

// ---------------------------------------------------------------------------
// APPNP step, CSR gather form. One wave per target node, lanes 0..39=channels.
// out = (1-a) * (sum_e w_e * h[src_e] + dinv^2 * h[node]) + a * h0[node]
// ---------------------------------------------------------------------------
__global__ __launch_bounds__(256) void appnp_csr_kernel(
    const int* __restrict__ offs, const int* __restrict__ csr_src,
    const float* __restrict__ csr_w, const float* __restrict__ dinv,
    const float* __restrict__ h, const float* __restrict__ h0,
    float* __restrict__ out)
{
    const int node = blockIdx.x * 4 + (threadIdx.x >> 6);
    const int lane = threadIdx.x & 63;
    if (node >= N_NODES || lane >= OUT_C) return;

    const int start = offs[node];
    const int end   = offs[node + 1];

    float acc = 0.0f;
    int e = start;
    for (; e + 2 <= end; e += 2) {
        const int   s0 = csr_src[e],   s1 = csr_src[e + 1];
        const float w0 = csr_w[e],     w1 = csr_w[e + 1];
        const float v0 = h[(size_t)s0 * OUT_C + lane];
        const float v1 = h[(size_t)s1 * OUT_C + lane];
        acc += w0 * v0 + w1 * v1;
    }
    if (e < end) {
        acc += csr_w[e] * h[(size_t)csr_src[e] * OUT_C + lane];
    }

    const float d = dinv[node];
    const size_t idx = (size_t)node * OUT_C + lane;
    out[idx] = (1.0f - ALPHA) * (acc + d * d * h[idx]) + ALPHA * h0[idx];
}

// ---------------------------------------------------------------------------
extern "C" void kernel_launch(void* const* d_in, const int* in_sizes, int n_in,
                              void* d_out, int out_size, void* d_ws, size_t ws_size,
                              hipStream_t stream) {
    const float* x   = (const float*)d_in[0];
    const int*   ei  = (const int*)d_in[1];     // [2, E] int32 on device
    const float* W1  = (const float*)d_in[2];
    const float* b1  = (const float*)d_in[3];
    const float* g1  = (const float*)d_in[4];
    const float* be1 = (const float*)d_in[5];
    const float* W2  = (const float*)d_in[6];
    const float* b2  = (const float*)d_in[7];
    const float* g2  = (const float*)d_in[8];
    const float* be2 = (const float*)d_in[9];
    const float* W3  = (const float*)d_in[10];
    const float* b3  = (const float*)d_in[11];
    float* out = (float*)d_out;

    const int* e_row = ei;
    const int* e_col = ei + N_EDGES;

    // workspace layout (4-byte units):
    //   dinv[N] | cnt[N] | offs[N+1] | bsum[128] | t1[N*256] | t2[N*256]
    // h0/hA/hB alias t1 (dead after GEMM2); csr_src/csr_w alias t2 (dead after gemm3)
    float* ws    = (float*)d_ws;
    float* dinv  = ws;
    int*   cnt   = (int*)(ws + N_NODES);
    int*   offs  = (int*)(ws + 2 * N_NODES);
    int*   bsum  = (int*)(ws + 3 * N_NODES + 1);
    float* t1    = ws + 3 * N_NODES + 1 + 128;
    float* t2    = t1 + (size_t)N_NODES * HID;

    float* h0    = t1;
    float* hA    = t1 + (size_t)N_NODES * OUT_C;
    float* hB    = t1 + (size_t)N_NODES * OUT_C * 2;
    int*   csr_src = (int*)t2;
    float* csr_w   = t2 + N_EDGES;

    // --- degree / dinv / offsets ---
    hipMemsetAsync(cnt, 0, N_NODES * sizeof(int), stream);
    deg_count_kernel<<<(N_EDGES + 255) / 256, 256, 0, stream>>>(e_col, cnt, N_EDGES);
    dinv_kernel<<<(N_NODES + 255) / 256, 256, 0, stream>>>(cnt, dinv, N_NODES);
    scan_partial_kernel<<<NBLK_SCAN, 256, 0, stream>>>(cnt, bsum);
    scan_bsum_kernel<<<1, 128, 0, stream>>>(bsum, NBLK_SCAN);
    scan_final_kernel<<<NBLK_SCAN, 256, 0, stream>>>(cnt, bsum, offs);
    set_total_kernel<<<1, 64, 0, stream>>>(offs);

    // --- MLP ---
    {
        dim3 grid(HID / BN, (N_NODES + BM - 1) / BM);
        gemm_bias_gelu_kernel<<<grid, 256, 0, stream>>>(x, W1, b1, t1, N_NODES, HID, IN_C, 1);
        layernorm_kernel<<<(N_NODES + 3) / 4, 256, 0, stream>>>(t1, g1, be1, N_NODES);
        gemm_bias_gelu_kernel<<<grid, 256, 0, stream>>>(t1, W2, b2, t2, N_NODES, HID, HID, 1);
        layernorm_kernel<<<(N_NODES + 3) / 4, 256, 0, stream>>>(t2, g2, be2, N_NODES);
        gemm3_kernel<<<2048, 256, 0, stream>>>(t2, W3, b3, h0, N_NODES);
    }

    // --- CSR build (t2 is dead now; cnt reused as fill cursor) ---
    hipMemsetAsync(cnt, 0, N_NODES * sizeof(int), stream);
    csr_fill_kernel<<<(N_EDGES + 255) / 256, 256, 0, stream>>>(
        e_row, e_col, dinv, offs, cnt, csr_src, csr_w, N_EDGES);

    // --- APPNP: 10 gather steps, no atomics ---
    const float* hcur = h0;
    for (int it = 0; it < K_ITERS; it++) {
        float* tgt = (it == K_ITERS - 1) ? out : ((it & 1) ? hB : hA);
        appnp_csr_kernel<<<(N_NODES + 3) / 4, 256, 0, stream>>>(
            offs, csr_src, csr_w, dinv, hcur, h0, tgt);
        hcur = tgt;
    }
}

// Round 3
// 1930.699 us; speedup vs baseline: 2.8163x; 1.2615x over previous
//
#include <hip/hip_runtime.h>
#include <hip/hip_bf16.h>
#include <math.h>

#define N_NODES 100000
#define N_EDGES 1600000
#define IN_C    500
#define HID     256
#define OUT_C   40
#define K_ITERS 10
#define ALPHA   0.1f
#define LN_EPS  1e-5f

#define SCAN_CHUNK 1024
#define NBLK_SCAN  ((N_NODES + SCAN_CHUNK - 1) / SCAN_CHUNK)   // 98

typedef __attribute__((ext_vector_type(8))) short bf16x8;
typedef __attribute__((ext_vector_type(4))) float f32x4;

// ---------------------------------------------------------------------------
// degree count / dinv
// ---------------------------------------------------------------------------
__global__ void deg_count_kernel(const int* __restrict__ col, int* __restrict__ cnt, int e) {
    int i = blockIdx.x * blockDim.x + threadIdx.x;
    if (i < e) atomicAdd(&cnt[col[i]], 1);
}

__global__ void dinv_kernel(const int* __restrict__ cnt, float* __restrict__ dinv, int n) {
    int i = blockIdx.x * blockDim.x + threadIdx.x;
    if (i < n) dinv[i] = rsqrtf((float)cnt[i] + 1.0f);  // +1 = self loop
}

// ---------------------------------------------------------------------------
// 3-kernel exclusive scan of cnt[N] -> offs[N] (+ offs[N]=E)
// ---------------------------------------------------------------------------
__global__ __launch_bounds__(256) void scan_partial_kernel(const int* __restrict__ cnt,
                                                           int* __restrict__ bsum) {
    __shared__ int s[256];
    const int base = blockIdx.x * SCAN_CHUNK;
    const int t = threadIdx.x;
    int sum = 0;
    #pragma unroll
    for (int j = 0; j < 4; j++) {
        int idx = base + t * 4 + j;
        if (idx < N_NODES) sum += cnt[idx];
    }
    s[t] = sum;
    __syncthreads();
    for (int off = 128; off > 0; off >>= 1) {
        if (t < off) s[t] += s[t + off];
        __syncthreads();
    }
    if (t == 0) bsum[blockIdx.x] = s[0];
}

__global__ __launch_bounds__(128) void scan_bsum_kernel(int* __restrict__ bsum, int nblk) {
    __shared__ int s[128];
    const int t = threadIdx.x;
    const int orig = (t < nblk) ? bsum[t] : 0;
    s[t] = orig;
    __syncthreads();
    for (int off = 1; off < 128; off <<= 1) {
        int v = 0;
        if (t >= off) v = s[t - off];
        __syncthreads();
        s[t] += v;
        __syncthreads();
    }
    if (t < nblk) bsum[t] = s[t] - orig;   // exclusive
}

__global__ __launch_bounds__(256) void scan_final_kernel(const int* __restrict__ cnt,
                                                         const int* __restrict__ bsum,
                                                         int* __restrict__ offs) {
    __shared__ int s[256];
    const int base = blockIdx.x * SCAN_CHUNK;
    const int t = threadIdx.x;
    int v[4];
    int lsum = 0;
    #pragma unroll
    for (int j = 0; j < 4; j++) {
        int idx = base + t * 4 + j;
        v[j] = (idx < N_NODES) ? cnt[idx] : 0;
        lsum += v[j];
    }
    s[t] = lsum;
    __syncthreads();
    const int orig = lsum;
    for (int off = 1; off < 256; off <<= 1) {
        int u = 0;
        if (t >= off) u = s[t - off];
        __syncthreads();
        s[t] += u;
        __syncthreads();
    }
    int run = bsum[blockIdx.x] + (s[t] - orig);
    #pragma unroll
    for (int j = 0; j < 4; j++) {
        int idx = base + t * 4 + j;
        if (idx < N_NODES) offs[idx] = run;
        run += v[j];
    }
}

__global__ void set_total_kernel(int* __restrict__ offs) {
    if (threadIdx.x == 0 && blockIdx.x == 0) offs[N_NODES] = N_EDGES;
}

// ---------------------------------------------------------------------------
// CSR fill: group edges by target col; weight = dinv[row]*dinv[col]
// ---------------------------------------------------------------------------
__global__ void csr_fill_kernel(const int* __restrict__ row, const int* __restrict__ col,
                                const float* __restrict__ dinv, const int* __restrict__ offs,
                                int* __restrict__ cursor, int* __restrict__ csr_src,
                                float* __restrict__ csr_w, int e) {
    int i = blockIdx.x * blockDim.x + threadIdx.x;
    if (i >= e) return;
    const int r = row[i], c = col[i];
    const int p = offs[c] + atomicAdd(&cursor[c], 1);
    csr_src[p] = r;
    csr_w[p]   = dinv[r] * dinv[c];
}

// ---------------------------------------------------------------------------
// split-bf16 MFMA GEMM: C[M,256] = gelu(A[M,K] @ B[K,256] + bias)
// fp32 inputs split into bf16 hi/lo during LDS staging (3-term Markidis:
// hi*hi + hi*lo + lo*hi, fp32 accumulate -> ~fp32 precision at MFMA rate).
// 128x128 block tile, BK=32, 4 waves (2x2), 64x64 per wave.
// ---------------------------------------------------------------------------
#define GBM 128
#define GBN 128
#define GBK 32
#define LDK 40   // padded LDS k-extent (shorts): 80 B rows -> 2-way banks (free)

__device__ __forceinline__ void split2(float a, short& hi, short& lo) {
    const unsigned ua = __float_as_uint(a);
    hi = (short)(ua >> 16);                                   // truncate: lo absorbs error
    const float r = a - __uint_as_float(ua & 0xffff0000u);
    lo = (short)(__float_as_uint(r) >> 16);
}

__global__ __launch_bounds__(256) void gemm_mfma_kernel(
    const float* __restrict__ A, const float* __restrict__ B,
    const float* __restrict__ bias, float* __restrict__ C,
    int M, int K, int do_gelu)
{
    __shared__ short As[2][GBM][LDK];   // [hi/lo][m][k]
    __shared__ short Bs[2][GBN][LDK];   // [hi/lo][n][k]

    const int tid  = threadIdx.x;
    const int row0 = blockIdx.y * GBM;
    const int col0 = blockIdx.x * GBN;

    const int wid  = tid >> 6;
    const int lane = tid & 63;
    const int wm   = wid >> 1;          // 0..1
    const int wn   = wid & 1;           // 0..1
    const int fm   = lane & 15;         // frag row (A) / col (B)
    const int fq   = lane >> 4;         // 0..3

    // staging roles
    const int a_m = tid >> 1;           // 0..127
    const int a_h = tid & 1;            // k half (16 floats)
    const int b_n = tid & 127;          // 0..127
    const int b_g = tid >> 7;           // k half

    f32x4 acc[4][4] = {};

    const int Ksteps = (K + GBK - 1) / GBK;
    for (int ks = 0; ks < Ksteps; ks++) {
        const int k0 = ks * GBK;
        const bool kfull = (k0 + GBK <= K);

        // ---- stage A tile: 128x32 fp32 -> hi/lo bf16 ----
        {
            const int gr = row0 + a_m;
            bf16x8 h0, h1, l0, l1;
            if (kfull && gr < M) {
                const float4* ap = reinterpret_cast<const float4*>(A + (size_t)gr * K + k0 + a_h * 16);
                #pragma unroll
                for (int i = 0; i < 4; i++) {
                    const float4 v = ap[i];
                    short th, tl;
                    split2(v.x, th, tl); if (i < 2) { h0[i*4+0] = th; l0[i*4+0] = tl; } else { h1[(i-2)*4+0] = th; l1[(i-2)*4+0] = tl; }
                    split2(v.y, th, tl); if (i < 2) { h0[i*4+1] = th; l0[i*4+1] = tl; } else { h1[(i-2)*4+1] = th; l1[(i-2)*4+1] = tl; }
                    split2(v.z, th, tl); if (i < 2) { h0[i*4+2] = th; l0[i*4+2] = tl; } else { h1[(i-2)*4+2] = th; l1[(i-2)*4+2] = tl; }
                    split2(v.w, th, tl); if (i < 2) { h0[i*4+3] = th; l0[i*4+3] = tl; } else { h1[(i-2)*4+3] = th; l1[(i-2)*4+3] = tl; }
                }
            } else {
                #pragma unroll
                for (int i = 0; i < 16; i++) {
                    const int gk = k0 + a_h * 16 + i;
                    const float v = (gr < M && gk < K) ? A[(size_t)gr * K + gk] : 0.0f;
                    short th, tl;
                    split2(v, th, tl);
                    if (i < 8) { h0[i] = th; l0[i] = tl; } else { h1[i-8] = th; l1[i-8] = tl; }
                }
            }
            *(bf16x8*)&As[0][a_m][a_h * 16]     = h0;
            *(bf16x8*)&As[0][a_m][a_h * 16 + 8] = h1;
            *(bf16x8*)&As[1][a_m][a_h * 16]     = l0;
            *(bf16x8*)&As[1][a_m][a_h * 16 + 8] = l1;
        }

        // ---- stage B tile: 32x128 fp32 -> hi/lo bf16, transposed to [n][k] ----
        {
            const int gc = col0 + b_n;  // always < 256
            bf16x8 h0, h1, l0, l1;
            #pragma unroll
            for (int j = 0; j < 16; j++) {
                const int gk = k0 + b_g * 16 + j;
                const float v = (kfull || gk < K) ? B[(size_t)gk * 256 + gc] : 0.0f;
                short th, tl;
                split2(v, th, tl);
                if (j < 8) { h0[j] = th; l0[j] = tl; } else { h1[j-8] = th; l1[j-8] = tl; }
            }
            *(bf16x8*)&Bs[0][b_n][b_g * 16]     = h0;
            *(bf16x8*)&Bs[0][b_n][b_g * 16 + 8] = h1;
            *(bf16x8*)&Bs[1][b_n][b_g * 16]     = l0;
            *(bf16x8*)&Bs[1][b_n][b_g * 16 + 8] = l1;
        }

        __syncthreads();

        // ---- MFMA: A frag A[m=lane&15][k=fq*8+j]; B frag B[n=lane&15][k=fq*8+j]
        bf16x8 a_hi[4], a_lo[4];
        #pragma unroll
        for (int tm = 0; tm < 4; tm++) {
            const int r = wm * 64 + tm * 16 + fm;
            a_hi[tm] = *(const bf16x8*)&As[0][r][fq * 8];
            a_lo[tm] = *(const bf16x8*)&As[1][r][fq * 8];
        }
        #pragma unroll
        for (int tn = 0; tn < 4; tn++) {
            const int c = wn * 64 + tn * 16 + fm;
            const bf16x8 b_hi = *(const bf16x8*)&Bs[0][c][fq * 8];
            const bf16x8 b_lo = *(const bf16x8*)&Bs[1][c][fq * 8];
            #pragma unroll
            for (int tm = 0; tm < 4; tm++) {
                acc[tm][tn] = __builtin_amdgcn_mfma_f32_16x16x32_bf16(a_hi[tm], b_hi, acc[tm][tn], 0, 0, 0);
                acc[tm][tn] = __builtin_amdgcn_mfma_f32_16x16x32_bf16(a_hi[tm], b_lo, acc[tm][tn], 0, 0, 0);
                acc[tm][tn] = __builtin_amdgcn_mfma_f32_16x16x32_bf16(a_lo[tm], b_hi, acc[tm][tn], 0, 0, 0);
            }
        }
        __syncthreads();
    }

    // ---- epilogue: C/D layout col=lane&15, row=fq*4+r ----
    #pragma unroll
    for (int tm = 0; tm < 4; tm++) {
        #pragma unroll
        for (int tn = 0; tn < 4; tn++) {
            const int gc = col0 + wn * 64 + tn * 16 + fm;
            const float bv = bias[gc];
            #pragma unroll
            for (int r = 0; r < 4; r++) {
                const int gr = row0 + wm * 64 + tm * 16 + fq * 4 + r;
                if (gr < M) {
                    float v = acc[tm][tn][r] + bv;
                    if (do_gelu) v = 0.5f * v * (1.0f + erff(v * 0.70710678118654752f));
                    C[(size_t)gr * 256 + gc] = v;
                }
            }
        }
    }
}

// ---------------------------------------------------------------------------
// LayerNorm over last dim (256), in place. One wave per row, 4 rows/block.
// ---------------------------------------------------------------------------
__global__ __launch_bounds__(256) void layernorm_kernel(
    float* __restrict__ h, const float* __restrict__ g, const float* __restrict__ b, int nrows)
{
    const int wave = threadIdx.x >> 6;
    const int lane = threadIdx.x & 63;
    const int row  = blockIdx.x * 4 + wave;
    if (row >= nrows) return;

    float* p = h + (size_t)row * HID;
    float v[4];
    float s = 0.0f;
    #pragma unroll
    for (int j = 0; j < 4; j++) { v[j] = p[lane + 64 * j]; s += v[j]; }
    #pragma unroll
    for (int off = 32; off > 0; off >>= 1) s += __shfl_xor(s, off);
    const float mu = s * (1.0f / 256.0f);

    float vs = 0.0f;
    #pragma unroll
    for (int j = 0; j < 4; j++) { float d = v[j] - mu; vs += d * d; }
    #pragma unroll
    for (int off = 32; off > 0; off >>= 1) vs += __shfl_xor(vs, off);
    const float rs = rsqrtf(vs * (1.0f / 256.0f) + LN_EPS);

    #pragma unroll
    for (int j = 0; j < 4; j++) {
        int c = lane + 64 * j;
        p[c] = (v[j] - mu) * rs * g[c] + b[c];
    }
}

// ---------------------------------------------------------------------------
// GEMM3: [N,256] @ [256,40] + b3, W3 staged in LDS (40 KB)
// ---------------------------------------------------------------------------
__global__ __launch_bounds__(256) void gemm3_kernel(
    const float* __restrict__ A, const float* __restrict__ W,
    const float* __restrict__ bias, float* __restrict__ C, int M)
{
    __shared__ float Ws[HID * OUT_C];
    __shared__ float bs[OUT_C];
    for (int i = threadIdx.x; i < HID * OUT_C; i += 256) Ws[i] = W[i];
    if (threadIdx.x < OUT_C) bs[threadIdx.x] = bias[threadIdx.x];
    __syncthreads();

    const int total = M * OUT_C;
    for (int idx = blockIdx.x * 256 + threadIdx.x; idx < total; idx += gridDim.x * 256) {
        const int r = idx / OUT_C;
        const int c = idx - r * OUT_C;
        const float4* a4 = reinterpret_cast<const float4*>(A + (size_t)r * HID);
        float s = 0.0f;
        #pragma unroll 4
        for (int k4 = 0; k4 < HID / 4; k4++) {
            float4 av = a4[k4];
            const float* wp = &Ws[k4 * 4 * OUT_C + c];
            s += av.x * wp[0] + av.y * wp[OUT_C] + av.z * wp[2 * OUT_C] + av.w * wp[3 * OUT_C];
        }
        C[idx] = s + bs[c];
    }
}

// ---------------------------------------------------------------------------
// APPNP step, CSR gather form. One wave per target node, lanes 0..39=channels.
// ---------------------------------------------------------------------------
__global__ __launch_bounds__(256) void appnp_csr_kernel(
    const int* __restrict__ offs, const int* __restrict__ csr_src,
    const float* __restrict__ csr_w, const float* __restrict__ dinv,
    const float* __restrict__ h, const float* __restrict__ h0,
    float* __restrict__ out)
{
    const int node = blockIdx.x * 4 + (threadIdx.x >> 6);
    const int lane = threadIdx.x & 63;
    if (node >= N_NODES || lane >= OUT_C) return;

    const int start = offs[node];
    const int end   = offs[node + 1];

    float acc = 0.0f;
    int e = start;
    for (; e + 2 <= end; e += 2) {
        const int   s0 = csr_src[e],   s1 = csr_src[e + 1];
        const float w0 = csr_w[e],     w1 = csr_w[e + 1];
        const float v0 = h[(size_t)s0 * OUT_C + lane];
        const float v1 = h[(size_t)s1 * OUT_C + lane];
        acc += w0 * v0 + w1 * v1;
    }
    if (e < end) {
        acc += csr_w[e] * h[(size_t)csr_src[e] * OUT_C + lane];
    }

    const float d = dinv[node];
    const size_t idx = (size_t)node * OUT_C + lane;
    out[idx] = (1.0f - ALPHA) * (acc + d * d * h[idx]) + ALPHA * h0[idx];
}

// ---------------------------------------------------------------------------
extern "C" void kernel_launch(void* const* d_in, const int* in_sizes, int n_in,
                              void* d_out, int out_size, void* d_ws, size_t ws_size,
                              hipStream_t stream) {
    const float* x   = (const float*)d_in[0];
    const int*   ei  = (const int*)d_in[1];     // [2, E] int32 on device
    const float* W1  = (const float*)d_in[2];
    const float* b1  = (const float*)d_in[3];
    const float* g1  = (const float*)d_in[4];
    const float* be1 = (const float*)d_in[5];
    const float* W2  = (const float*)d_in[6];
    const float* b2  = (const float*)d_in[7];
    const float* g2  = (const float*)d_in[8];
    const float* be2 = (const float*)d_in[9];
    const float* W3  = (const float*)d_in[10];
    const float* b3  = (const float*)d_in[11];
    float* out = (float*)d_out;

    const int* e_row = ei;
    const int* e_col = ei + N_EDGES;

    // workspace layout (4-byte units):
    //   dinv[N] | cnt[N] | offs[N+1] | bsum[128] | t1[N*256] | t2[N*256]
    // h0/hA/hB alias t1 (dead after GEMM2); csr_src/csr_w alias t2 (dead after gemm3)
    float* ws    = (float*)d_ws;
    float* dinv  = ws;
    int*   cnt   = (int*)(ws + N_NODES);
    int*   offs  = (int*)(ws + 2 * N_NODES);
    int*   bsum  = (int*)(ws + 3 * N_NODES + 1);
    float* t1    = ws + 3 * N_NODES + 1 + 128;
    float* t2    = t1 + (size_t)N_NODES * HID;

    float* h0    = t1;
    float* hA    = t1 + (size_t)N_NODES * OUT_C;
    float* hB    = t1 + (size_t)N_NODES * OUT_C * 2;
    int*   csr_src = (int*)t2;
    float* csr_w   = t2 + N_EDGES;

    // --- degree / dinv / offsets ---
    hipMemsetAsync(cnt, 0, N_NODES * sizeof(int), stream);
    deg_count_kernel<<<(N_EDGES + 255) / 256, 256, 0, stream>>>(e_col, cnt, N_EDGES);
    dinv_kernel<<<(N_NODES + 255) / 256, 256, 0, stream>>>(cnt, dinv, N_NODES);
    scan_partial_kernel<<<NBLK_SCAN, 256, 0, stream>>>(cnt, bsum);
    scan_bsum_kernel<<<1, 128, 0, stream>>>(bsum, NBLK_SCAN);
    scan_final_kernel<<<NBLK_SCAN, 256, 0, stream>>>(cnt, bsum, offs);
    set_total_kernel<<<1, 64, 0, stream>>>(offs);

    // --- MLP (split-bf16 MFMA GEMMs) ---
    {
        dim3 grid(HID / GBN, (N_NODES + GBM - 1) / GBM);   // (2, 782)
        gemm_mfma_kernel<<<grid, 256, 0, stream>>>(x, W1, b1, t1, N_NODES, IN_C, 1);
        layernorm_kernel<<<(N_NODES + 3) / 4, 256, 0, stream>>>(t1, g1, be1, N_NODES);
        gemm_mfma_kernel<<<grid, 256, 0, stream>>>(t1, W2, b2, t2, N_NODES, HID, 1);
        layernorm_kernel<<<(N_NODES + 3) / 4, 256, 0, stream>>>(t2, g2, be2, N_NODES);
        gemm3_kernel<<<2048, 256, 0, stream>>>(t2, W3, b3, h0, N_NODES);
    }

    // --- CSR build (t2 is dead now; cnt reused as fill cursor) ---
    hipMemsetAsync(cnt, 0, N_NODES * sizeof(int), stream);
    csr_fill_kernel<<<(N_EDGES + 255) / 256, 256, 0, stream>>>(
        e_row, e_col, dinv, offs, cnt, csr_src, csr_w, N_EDGES);

    // --- APPNP: 10 gather steps, no atomics ---
    const float* hcur = h0;
    for (int it = 0; it < K_ITERS; it++) {
        float* tgt = (it == K_ITERS - 1) ? out : ((it & 1) ? hB : hA);
        appnp_csr_kernel<<<(N_NODES + 3) / 4, 256, 0, stream>>>(
            offs, csr_src, csr_w, dinv, hcur, h0, tgt);
        hcur = tgt;
    }
}

// Round 4
// 1729.729 us; speedup vs baseline: 3.1435x; 1.1162x over previous
//
#include <hip/hip_runtime.h>
#include <hip/hip_bf16.h>
#include <math.h>

#define N_NODES 100000
#define N_EDGES 1600000
#define IN_C    500
#define HID     256
#define OUT_C   40
#define K_ITERS 10
#define ALPHA   0.1f
#define LN_EPS  1e-5f

#define K1PAD   512
#define K2PAD   256

#define SCAN_CHUNK 1024
#define NBLK_SCAN  ((N_NODES + SCAN_CHUNK - 1) / SCAN_CHUNK)   // 98

typedef __attribute__((ext_vector_type(8))) short bf16x8;
typedef __attribute__((ext_vector_type(4))) float f32x4;

// ---------------------------------------------------------------------------
// fp32 -> bf16 hi/lo split (3-term Markidis; lo absorbs truncation error)
// ---------------------------------------------------------------------------
__device__ __forceinline__ void split2(float a, short& hi, short& lo) {
    const unsigned ua = __float_as_uint(a);
    hi = (short)(ua >> 16);
    const float r = a - __uint_as_float(ua & 0xffff0000u);
    lo = (short)(__float_as_uint(r) >> 16);
}

__device__ __forceinline__ void async_load16(const void* g, void* l) {
    __builtin_amdgcn_global_load_lds(
        (const __attribute__((address_space(1))) void*)g,
        (__attribute__((address_space(3))) void*)l, 16, 0, 0);
}

// ---------------------------------------------------------------------------
// degree count / dinv
// ---------------------------------------------------------------------------
__global__ void deg_count_kernel(const int* __restrict__ col, int* __restrict__ cnt, int e) {
    int i = blockIdx.x * blockDim.x + threadIdx.x;
    if (i < e) atomicAdd(&cnt[col[i]], 1);
}

__global__ void dinv_kernel(const int* __restrict__ cnt, float* __restrict__ dinv, int n) {
    int i = blockIdx.x * blockDim.x + threadIdx.x;
    if (i < n) dinv[i] = rsqrtf((float)cnt[i] + 1.0f);  // +1 = self loop
}

// ---------------------------------------------------------------------------
// 3-kernel exclusive scan of cnt[N] -> offs[N] (+ offs[N]=E)
// ---------------------------------------------------------------------------
__global__ __launch_bounds__(256) void scan_partial_kernel(const int* __restrict__ cnt,
                                                           int* __restrict__ bsum) {
    __shared__ int s[256];
    const int base = blockIdx.x * SCAN_CHUNK;
    const int t = threadIdx.x;
    int sum = 0;
    #pragma unroll
    for (int j = 0; j < 4; j++) {
        int idx = base + t * 4 + j;
        if (idx < N_NODES) sum += cnt[idx];
    }
    s[t] = sum;
    __syncthreads();
    for (int off = 128; off > 0; off >>= 1) {
        if (t < off) s[t] += s[t + off];
        __syncthreads();
    }
    if (t == 0) bsum[blockIdx.x] = s[0];
}

__global__ __launch_bounds__(128) void scan_bsum_kernel(int* __restrict__ bsum, int nblk) {
    __shared__ int s[128];
    const int t = threadIdx.x;
    const int orig = (t < nblk) ? bsum[t] : 0;
    s[t] = orig;
    __syncthreads();
    for (int off = 1; off < 128; off <<= 1) {
        int v = 0;
        if (t >= off) v = s[t - off];
        __syncthreads();
        s[t] += v;
        __syncthreads();
    }
    if (t < nblk) bsum[t] = s[t] - orig;   // exclusive
}

__global__ __launch_bounds__(256) void scan_final_kernel(const int* __restrict__ cnt,
                                                         const int* __restrict__ bsum,
                                                         int* __restrict__ offs) {
    __shared__ int s[256];
    const int base = blockIdx.x * SCAN_CHUNK;
    const int t = threadIdx.x;
    int v[4];
    int lsum = 0;
    #pragma unroll
    for (int j = 0; j < 4; j++) {
        int idx = base + t * 4 + j;
        v[j] = (idx < N_NODES) ? cnt[idx] : 0;
        lsum += v[j];
    }
    s[t] = lsum;
    __syncthreads();
    const int orig = lsum;
    for (int off = 1; off < 256; off <<= 1) {
        int u = 0;
        if (t >= off) u = s[t - off];
        __syncthreads();
        s[t] += u;
        __syncthreads();
    }
    int run = bsum[blockIdx.x] + (s[t] - orig);
    #pragma unroll
    for (int j = 0; j < 4; j++) {
        int idx = base + t * 4 + j;
        if (idx < N_NODES) offs[idx] = run;
        run += v[j];
    }
}

__global__ void set_total_kernel(int* __restrict__ offs) {
    if (threadIdx.x == 0 && blockIdx.x == 0) offs[N_NODES] = N_EDGES;
}

// ---------------------------------------------------------------------------
// CSR fill: group edges by target col; weight = dinv[row]*dinv[col]
// ---------------------------------------------------------------------------
__global__ void csr_fill_kernel(const int* __restrict__ row, const int* __restrict__ col,
                                const float* __restrict__ dinv, const int* __restrict__ offs,
                                int* __restrict__ cursor, int* __restrict__ csr_src,
                                float* __restrict__ csr_w, int e) {
    int i = blockIdx.x * blockDim.x + threadIdx.x;
    if (i >= e) return;
    const int r = row[i], c = col[i];
    const int p = offs[c] + atomicAdd(&cursor[c], 1);
    csr_src[p] = r;
    csr_w[p]   = dinv[r] * dinv[c];
}

// ---------------------------------------------------------------------------
// split fp32 [M,K] -> bf16 hi/lo planes [M,Kpad] (zero-padded K..Kpad)
// ---------------------------------------------------------------------------
__global__ __launch_bounds__(256) void split_pad_kernel(
    const float* __restrict__ A, short* __restrict__ hi, short* __restrict__ lo,
    int M, int K, int Kpad)
{
    const size_t total = (size_t)M * (Kpad / 4);
    const size_t idx = (size_t)blockIdx.x * 256 + threadIdx.x;
    if (idx >= total) return;
    const int r  = (int)(idx / (Kpad / 4));
    const int k4 = (int)(idx - (size_t)r * (Kpad / 4)) * 4;
    short4 h, l;
    if (k4 + 4 <= K) {
        const float4 v = *reinterpret_cast<const float4*>(A + (size_t)r * K + k4);
        split2(v.x, h.x, l.x); split2(v.y, h.y, l.y);
        split2(v.z, h.z, l.z); split2(v.w, h.w, l.w);
    } else {
        float vv[4];
        #pragma unroll
        for (int j = 0; j < 4; j++) vv[j] = (k4 + j < K) ? A[(size_t)r * K + k4 + j] : 0.0f;
        split2(vv[0], h.x, l.x); split2(vv[1], h.y, l.y);
        split2(vv[2], h.z, l.z); split2(vv[3], h.w, l.w);
    }
    *reinterpret_cast<short4*>(hi + (size_t)r * Kpad + k4) = h;
    *reinterpret_cast<short4*>(lo + (size_t)r * Kpad + k4) = l;
}

// W [K,N] fp32 -> transposed hi/lo planes [N,Kpad]
__global__ __launch_bounds__(256) void wsplit_kernel(
    const float* __restrict__ W, short* __restrict__ hi, short* __restrict__ lo,
    int K, int Nn, int Kpad)
{
    const int idx = blockIdx.x * 256 + threadIdx.x;
    if (idx >= Nn * Kpad) return;
    const int n = idx / Kpad, k = idx - n * Kpad;
    const float v = (k < K) ? W[(size_t)k * Nn + n] : 0.0f;
    short h, l;
    split2(v, h, l);
    hi[idx] = h;
    lo[idx] = l;
}

// ---------------------------------------------------------------------------
// split-bf16 MFMA GEMM, m97 pattern: global_load_lds(16B) staging of
// pre-split planes, ds_read_b128 fragments, 3 MFMA/term-pair, fp32 acc.
// A planes [M,Kpad], B planes [256,Kpad] (transposed). C = act(A@B + bias).
// 128x128 tile, BK=32, 4 waves (2x2), 64x64/wave. LDS 32 KB.
// ---------------------------------------------------------------------------
#define GBM 128
#define GBN 128
#define GBK 32

__global__ __launch_bounds__(256) void gemm_mfma2_kernel(
    const short* __restrict__ Ahi, const short* __restrict__ Alo,
    const short* __restrict__ Bhi, const short* __restrict__ Blo,
    const float* __restrict__ bias, float* __restrict__ C,
    int M, int Kpad, int do_gelu)
{
    __shared__ short As[2][GBM * GBK];   // [hi/lo][m*32+k], 64 B rows
    __shared__ short Bs[2][GBN * GBK];   // [hi/lo][n*32+k]

    const int tid  = threadIdx.x;
    const int wid  = tid >> 6;
    const int lane = tid & 63;
    const int wm   = wid >> 1, wn = wid & 1;
    const int fm   = lane & 15, fq = lane >> 4;
    const int row0 = blockIdx.y * GBM;
    const int col0 = blockIdx.x * GBN;

    f32x4 acc[4][4] = {};

    const int Ks = Kpad / GBK;
    for (int ks = 0; ks < Ks; ks++) {
        const int k0 = ks * GBK;
        __syncthreads();   // previous iter's ds_reads done before overwrite

        #pragma unroll
        for (int i = 0; i < 2; i++) {
            const int c  = i * 256 + tid;          // 16B-chunk index, per lane
            const int m  = c >> 2;
            const int k8 = (c & 3) * 8;
            const int cb = (i * 256 + wid * 64) * 8;   // wave-uniform LDS base (shorts)
            const int gmA = min(row0 + m, M - 1);      // clamp; OOB rows discarded
            const size_t oA = (size_t)gmA * Kpad + k0 + k8;
            const size_t oB = (size_t)(col0 + m) * Kpad + k0 + k8;
            async_load16(Ahi + oA, &As[0][cb]);
            async_load16(Alo + oA, &As[1][cb]);
            async_load16(Bhi + oB, &Bs[0][cb]);
            async_load16(Blo + oB, &Bs[1][cb]);
        }
        __syncthreads();   // drains vmcnt: LDS tiles ready

        bf16x8 ah[4], al[4];
        #pragma unroll
        for (int tm = 0; tm < 4; tm++) {
            const int r = wm * 64 + tm * 16 + fm;
            ah[tm] = *(const bf16x8*)&As[0][r * GBK + fq * 8];
            al[tm] = *(const bf16x8*)&As[1][r * GBK + fq * 8];
        }
        #pragma unroll
        for (int tn = 0; tn < 4; tn++) {
            const int cc = wn * 64 + tn * 16 + fm;
            const bf16x8 bh = *(const bf16x8*)&Bs[0][cc * GBK + fq * 8];
            const bf16x8 bl = *(const bf16x8*)&Bs[1][cc * GBK + fq * 8];
            #pragma unroll
            for (int tm = 0; tm < 4; tm++) {
                acc[tm][tn] = __builtin_amdgcn_mfma_f32_16x16x32_bf16(ah[tm], bh, acc[tm][tn], 0, 0, 0);
                acc[tm][tn] = __builtin_amdgcn_mfma_f32_16x16x32_bf16(ah[tm], bl, acc[tm][tn], 0, 0, 0);
                acc[tm][tn] = __builtin_amdgcn_mfma_f32_16x16x32_bf16(al[tm], bh, acc[tm][tn], 0, 0, 0);
            }
        }
    }

    // epilogue: C/D layout col=lane&15, row=fq*4+r
    #pragma unroll
    for (int tm = 0; tm < 4; tm++) {
        #pragma unroll
        for (int tn = 0; tn < 4; tn++) {
            const int gc = col0 + wn * 64 + tn * 16 + fm;
            const float bv = bias[gc];
            #pragma unroll
            for (int r = 0; r < 4; r++) {
                const int gr = row0 + wm * 64 + tm * 16 + fq * 4 + r;
                if (gr < M) {
                    float v = acc[tm][tn][r] + bv;
                    if (do_gelu) v = 0.5f * v * (1.0f + erff(v * 0.70710678118654752f));
                    C[(size_t)gr * 256 + gc] = v;
                }
            }
        }
    }
}

// ---------------------------------------------------------------------------
// LayerNorm(256) -> bf16 hi/lo planes [M,256] (feeds next MFMA GEMM)
// ---------------------------------------------------------------------------
__global__ __launch_bounds__(256) void layernorm_split_kernel(
    const float* __restrict__ h, const float* __restrict__ g, const float* __restrict__ b,
    short* __restrict__ hi, short* __restrict__ lo, int nrows)
{
    const int wave = threadIdx.x >> 6;
    const int lane = threadIdx.x & 63;
    const int row  = blockIdx.x * 4 + wave;
    if (row >= nrows) return;

    const float* p = h + (size_t)row * HID;
    float v[4];
    float s = 0.0f;
    #pragma unroll
    for (int j = 0; j < 4; j++) { v[j] = p[lane + 64 * j]; s += v[j]; }
    #pragma unroll
    for (int off = 32; off > 0; off >>= 1) s += __shfl_xor(s, off);
    const float mu = s * (1.0f / 256.0f);

    float vs = 0.0f;
    #pragma unroll
    for (int j = 0; j < 4; j++) { float d = v[j] - mu; vs += d * d; }
    #pragma unroll
    for (int off = 32; off > 0; off >>= 1) vs += __shfl_xor(vs, off);
    const float rs = rsqrtf(vs * (1.0f / 256.0f) + LN_EPS);

    #pragma unroll
    for (int j = 0; j < 4; j++) {
        const int c = lane + 64 * j;
        const float o = (v[j] - mu) * rs * g[c] + b[c];
        short th, tl;
        split2(o, th, tl);
        hi[(size_t)row * HID + c] = th;
        lo[(size_t)row * HID + c] = tl;
    }
}

// plain fp32 in-place LayerNorm (before gemm3)
__global__ __launch_bounds__(256) void layernorm_kernel(
    float* __restrict__ h, const float* __restrict__ g, const float* __restrict__ b, int nrows)
{
    const int wave = threadIdx.x >> 6;
    const int lane = threadIdx.x & 63;
    const int row  = blockIdx.x * 4 + wave;
    if (row >= nrows) return;

    float* p = h + (size_t)row * HID;
    float v[4];
    float s = 0.0f;
    #pragma unroll
    for (int j = 0; j < 4; j++) { v[j] = p[lane + 64 * j]; s += v[j]; }
    #pragma unroll
    for (int off = 32; off > 0; off >>= 1) s += __shfl_xor(s, off);
    const float mu = s * (1.0f / 256.0f);

    float vs = 0.0f;
    #pragma unroll
    for (int j = 0; j < 4; j++) { float d = v[j] - mu; vs += d * d; }
    #pragma unroll
    for (int off = 32; off > 0; off >>= 1) vs += __shfl_xor(vs, off);
    const float rs = rsqrtf(vs * (1.0f / 256.0f) + LN_EPS);

    #pragma unroll
    for (int j = 0; j < 4; j++) {
        int c = lane + 64 * j;
        p[c] = (v[j] - mu) * rs * g[c] + b[c];
    }
}

// ---------------------------------------------------------------------------
// GEMM3: [N,256] @ [256,40] + b3, W3 staged in LDS (40 KB)
// ---------------------------------------------------------------------------
__global__ __launch_bounds__(256) void gemm3_kernel(
    const float* __restrict__ A, const float* __restrict__ W,
    const float* __restrict__ bias, float* __restrict__ C, int M)
{
    __shared__ float Ws[HID * OUT_C];
    __shared__ float bs[OUT_C];
    for (int i = threadIdx.x; i < HID * OUT_C; i += 256) Ws[i] = W[i];
    if (threadIdx.x < OUT_C) bs[threadIdx.x] = bias[threadIdx.x];
    __syncthreads();

    const int total = M * OUT_C;
    for (int idx = blockIdx.x * 256 + threadIdx.x; idx < total; idx += gridDim.x * 256) {
        const int r = idx / OUT_C;
        const int c = idx - r * OUT_C;
        const float4* a4 = reinterpret_cast<const float4*>(A + (size_t)r * HID);
        float s = 0.0f;
        #pragma unroll 4
        for (int k4 = 0; k4 < HID / 4; k4++) {
            float4 av = a4[k4];
            const float* wp = &Ws[k4 * 4 * OUT_C + c];
            s += av.x * wp[0] + av.y * wp[OUT_C] + av.z * wp[2 * OUT_C] + av.w * wp[3 * OUT_C];
        }
        C[idx] = s + bs[c];
    }
}

// ---------------------------------------------------------------------------
// APPNP step, CSR gather, 8-deep unrolled for memory-level parallelism.
// One wave per target node, lanes 0..39 = channels.
// ---------------------------------------------------------------------------
__global__ __launch_bounds__(256) void appnp_csr_kernel(
    const int* __restrict__ offs, const int* __restrict__ csr_src,
    const float* __restrict__ csr_w, const float* __restrict__ dinv,
    const float* __restrict__ h, const float* __restrict__ h0,
    float* __restrict__ out)
{
    const int node = blockIdx.x * 4 + (threadIdx.x >> 6);
    const int lane = threadIdx.x & 63;
    if (node >= N_NODES || lane >= OUT_C) return;

    const int start = offs[node];
    const int end   = offs[node + 1];

    float acc = 0.0f;
    int e = start;
    // 8-edge blocks: 8 independent gathers in flight
    for (; e + 8 <= end; e += 8) {
        int s[8]; float w[8]; float v[8];
        #pragma unroll
        for (int j = 0; j < 8; j++) s[j] = csr_src[e + j];
        #pragma unroll
        for (int j = 0; j < 8; j++) w[j] = csr_w[e + j];
        #pragma unroll
        for (int j = 0; j < 8; j++) v[j] = h[(size_t)s[j] * OUT_C + lane];
        #pragma unroll
        for (int j = 0; j < 8; j++) acc += w[j] * v[j];
    }
    for (; e + 2 <= end; e += 2) {
        const int   s0 = csr_src[e], s1 = csr_src[e + 1];
        const float w0 = csr_w[e],   w1 = csr_w[e + 1];
        acc += w0 * h[(size_t)s0 * OUT_C + lane] + w1 * h[(size_t)s1 * OUT_C + lane];
    }
    if (e < end) acc += csr_w[e] * h[(size_t)csr_src[e] * OUT_C + lane];

    const float d = dinv[node];
    const size_t idx = (size_t)node * OUT_C + lane;
    out[idx] = (1.0f - ALPHA) * (acc + d * d * h[idx]) + ALPHA * h0[idx];
}

// ---------------------------------------------------------------------------
extern "C" void kernel_launch(void* const* d_in, const int* in_sizes, int n_in,
                              void* d_out, int out_size, void* d_ws, size_t ws_size,
                              hipStream_t stream) {
    const float* x   = (const float*)d_in[0];
    const int*   ei  = (const int*)d_in[1];
    const float* W1  = (const float*)d_in[2];
    const float* b1  = (const float*)d_in[3];
    const float* g1  = (const float*)d_in[4];
    const float* be1 = (const float*)d_in[5];
    const float* W2  = (const float*)d_in[6];
    const float* b2  = (const float*)d_in[7];
    const float* g2  = (const float*)d_in[8];
    const float* be2 = (const float*)d_in[9];
    const float* W3  = (const float*)d_in[10];
    const float* b3  = (const float*)d_in[11];
    float* out = (float*)d_out;

    const int* e_row = ei;
    const int* e_col = ei + N_EDGES;

    // ---- workspace layout (float units), regions aliased by liveness ----
    float* ws = (float*)d_ws;
    size_t off = 0;
    float* dinv = ws + off; off += N_NODES;
    int*   cnt  = (int*)(ws + off); off += N_NODES;
    int*   offs = (int*)(ws + off); off += N_NODES + 1;
    int*   bsum = (int*)(ws + off); off += 128;
    short* W1hi = (short*)(ws + off); off += 65536;   // 256*512 shorts
    short* W1lo = (short*)(ws + off); off += 65536;
    short* W2hi = (short*)(ws + off); off += 32768;   // 256*256 shorts
    short* W2lo = (short*)(ws + off); off += 32768;
    // Region B (25.6M floats): t1 (GEMM1 out), later t2 (GEMM2 out)
    float* t1 = ws + off; off += (size_t)N_NODES * HID;
    float* t2 = t1;
    // Region A (51.2M floats): A1 planes -> A2 planes -> csr + h buffers
    float* regA = ws + off; off += (size_t)N_NODES * K1PAD;   // 51.2M floats
    short* A1hi = (short*)regA;                               // 51.2M shorts
    short* A1lo = A1hi + (size_t)N_NODES * K1PAD;
    short* A2hi = (short*)regA;                               // 25.6M shorts
    short* A2lo = A2hi + (size_t)N_NODES * K2PAD;
    int*   csr_src = (int*)regA;
    float* csr_w   = regA + N_EDGES;
    float* h0 = regA + 2 * (size_t)N_EDGES;
    float* hA = h0 + (size_t)N_NODES * OUT_C;
    float* hB = hA + (size_t)N_NODES * OUT_C;

    // --- degree / dinv / offsets ---
    hipMemsetAsync(cnt, 0, N_NODES * sizeof(int), stream);
    deg_count_kernel<<<(N_EDGES + 255) / 256, 256, 0, stream>>>(e_col, cnt, N_EDGES);
    dinv_kernel<<<(N_NODES + 255) / 256, 256, 0, stream>>>(cnt, dinv, N_NODES);
    scan_partial_kernel<<<NBLK_SCAN, 256, 0, stream>>>(cnt, bsum);
    scan_bsum_kernel<<<1, 128, 0, stream>>>(bsum, NBLK_SCAN);
    scan_final_kernel<<<NBLK_SCAN, 256, 0, stream>>>(cnt, bsum, offs);
    set_total_kernel<<<1, 64, 0, stream>>>(offs);

    // --- pre-split inputs to bf16 hi/lo planes ---
    {
        const size_t chunks = (size_t)N_NODES * (K1PAD / 4);
        split_pad_kernel<<<(int)((chunks + 255) / 256), 256, 0, stream>>>(
            x, A1hi, A1lo, N_NODES, IN_C, K1PAD);
        wsplit_kernel<<<(256 * K1PAD + 255) / 256, 256, 0, stream>>>(W1, W1hi, W1lo, IN_C, 256, K1PAD);
        wsplit_kernel<<<(256 * K2PAD + 255) / 256, 256, 0, stream>>>(W2, W2hi, W2lo, HID, 256, K2PAD);
    }

    // --- MLP ---
    {
        dim3 grid(2, (N_NODES + GBM - 1) / GBM);   // (2, 782)
        gemm_mfma2_kernel<<<grid, 256, 0, stream>>>(A1hi, A1lo, W1hi, W1lo, b1, t1, N_NODES, K1PAD, 1);
        layernorm_split_kernel<<<(N_NODES + 3) / 4, 256, 0, stream>>>(t1, g1, be1, A2hi, A2lo, N_NODES);
        gemm_mfma2_kernel<<<grid, 256, 0, stream>>>(A2hi, A2lo, W2hi, W2lo, b2, t2, N_NODES, K2PAD, 1);
        layernorm_kernel<<<(N_NODES + 3) / 4, 256, 0, stream>>>(t2, g2, be2, N_NODES);
        gemm3_kernel<<<2048, 256, 0, stream>>>(t2, W3, b3, h0, N_NODES);
    }

    // --- CSR build (region A's planes dead; cnt reused as fill cursor) ---
    hipMemsetAsync(cnt, 0, N_NODES * sizeof(int), stream);
    csr_fill_kernel<<<(N_EDGES + 255) / 256, 256, 0, stream>>>(
        e_row, e_col, dinv, offs, cnt, csr_src, csr_w, N_EDGES);

    // --- APPNP: 10 gather steps ---
    const float* hcur = h0;
    for (int it = 0; it < K_ITERS; it++) {
        float* tgt = (it == K_ITERS - 1) ? out : ((it & 1) ? hB : hA);
        appnp_csr_kernel<<<(N_NODES + 3) / 4, 256, 0, stream>>>(
            offs, csr_src, csr_w, dinv, hcur, h0, tgt);
        hcur = tgt;
    }
}

// Round 5
// 1579.037 us; speedup vs baseline: 3.4435x; 1.0954x over previous
//
#include <hip/hip_runtime.h>
#include <hip/hip_bf16.h>
#include <math.h>

#define N_NODES 100000
#define N_EDGES 1600000
#define IN_C    500
#define HID     256
#define OUT_C   40
#define K_ITERS 10
#define ALPHA   0.1f
#define LN_EPS  1e-5f

#define K1PAD   512
#define K2PAD   256

#define SCAN_CHUNK 1024
#define NBLK_SCAN  ((N_NODES + SCAN_CHUNK - 1) / SCAN_CHUNK)   // 98

typedef __attribute__((ext_vector_type(8))) short bf16x8;
typedef __attribute__((ext_vector_type(4))) float f32x4;

// ---------------------------------------------------------------------------
// fp32 -> bf16 hi/lo split (3-term Markidis; lo absorbs truncation error)
// ---------------------------------------------------------------------------
__device__ __forceinline__ void split2(float a, short& hi, short& lo) {
    const unsigned ua = __float_as_uint(a);
    hi = (short)(ua >> 16);
    const float r = a - __uint_as_float(ua & 0xffff0000u);
    lo = (short)(__float_as_uint(r) >> 16);
}

__device__ __forceinline__ void async_load16(const void* g, void* l) {
    __builtin_amdgcn_global_load_lds(
        (const __attribute__((address_space(1))) void*)g,
        (__attribute__((address_space(3))) void*)l, 16, 0, 0);
}

// ---------------------------------------------------------------------------
// degree count / dinv
// ---------------------------------------------------------------------------
__global__ void deg_count_kernel(const int* __restrict__ col, int* __restrict__ cnt, int e) {
    int i = blockIdx.x * blockDim.x + threadIdx.x;
    if (i < e) atomicAdd(&cnt[col[i]], 1);
}

__global__ void dinv_kernel(const int* __restrict__ cnt, float* __restrict__ dinv, int n) {
    int i = blockIdx.x * blockDim.x + threadIdx.x;
    if (i < n) dinv[i] = rsqrtf((float)cnt[i] + 1.0f);  // +1 = self loop
}

// ---------------------------------------------------------------------------
// 3-kernel exclusive scan of cnt[N] -> offs[N] (+ offs[N]=E)
// ---------------------------------------------------------------------------
__global__ __launch_bounds__(256) void scan_partial_kernel(const int* __restrict__ cnt,
                                                           int* __restrict__ bsum) {
    __shared__ int s[256];
    const int base = blockIdx.x * SCAN_CHUNK;
    const int t = threadIdx.x;
    int sum = 0;
    #pragma unroll
    for (int j = 0; j < 4; j++) {
        int idx = base + t * 4 + j;
        if (idx < N_NODES) sum += cnt[idx];
    }
    s[t] = sum;
    __syncthreads();
    for (int off = 128; off > 0; off >>= 1) {
        if (t < off) s[t] += s[t + off];
        __syncthreads();
    }
    if (t == 0) bsum[blockIdx.x] = s[0];
}

__global__ __launch_bounds__(128) void scan_bsum_kernel(int* __restrict__ bsum, int nblk) {
    __shared__ int s[128];
    const int t = threadIdx.x;
    const int orig = (t < nblk) ? bsum[t] : 0;
    s[t] = orig;
    __syncthreads();
    for (int off = 1; off < 128; off <<= 1) {
        int v = 0;
        if (t >= off) v = s[t - off];
        __syncthreads();
        s[t] += v;
        __syncthreads();
    }
    if (t < nblk) bsum[t] = s[t] - orig;   // exclusive
}

__global__ __launch_bounds__(256) void scan_final_kernel(const int* __restrict__ cnt,
                                                         const int* __restrict__ bsum,
                                                         int* __restrict__ offs) {
    __shared__ int s[256];
    const int base = blockIdx.x * SCAN_CHUNK;
    const int t = threadIdx.x;
    int v[4];
    int lsum = 0;
    #pragma unroll
    for (int j = 0; j < 4; j++) {
        int idx = base + t * 4 + j;
        v[j] = (idx < N_NODES) ? cnt[idx] : 0;
        lsum += v[j];
    }
    s[t] = lsum;
    __syncthreads();
    const int orig = lsum;
    for (int off = 1; off < 256; off <<= 1) {
        int u = 0;
        if (t >= off) u = s[t - off];
        __syncthreads();
        s[t] += u;
        __syncthreads();
    }
    int run = bsum[blockIdx.x] + (s[t] - orig);
    #pragma unroll
    for (int j = 0; j < 4; j++) {
        int idx = base + t * 4 + j;
        if (idx < N_NODES) offs[idx] = run;
        run += v[j];
    }
}

__global__ void set_total_kernel(int* __restrict__ offs) {
    if (threadIdx.x == 0 && blockIdx.x == 0) offs[N_NODES] = N_EDGES;
}

// ---------------------------------------------------------------------------
// CSR fill: group edges by target col; packed (src, weight-bits) int2
// ---------------------------------------------------------------------------
__global__ void csr_fill_kernel(const int* __restrict__ row, const int* __restrict__ col,
                                const float* __restrict__ dinv, const int* __restrict__ offs,
                                int* __restrict__ cursor, int2* __restrict__ csr_ew, int e) {
    int i = blockIdx.x * blockDim.x + threadIdx.x;
    if (i >= e) return;
    const int r = row[i], c = col[i];
    const int p = offs[c] + atomicAdd(&cursor[c], 1);
    csr_ew[p] = make_int2(r, __float_as_int(dinv[r] * dinv[c]));
}

// ---------------------------------------------------------------------------
// W [K,N] fp32 -> transposed hi/lo planes [N,Kpad]
// ---------------------------------------------------------------------------
__global__ __launch_bounds__(256) void wsplit_kernel(
    const float* __restrict__ W, short* __restrict__ hi, short* __restrict__ lo,
    int K, int Nn, int Kpad)
{
    const int idx = blockIdx.x * 256 + threadIdx.x;
    if (idx >= Nn * Kpad) return;
    const int n = idx / Kpad, k = idx - n * Kpad;
    const float v = (k < K) ? W[(size_t)k * Nn + n] : 0.0f;
    short h, l;
    split2(v, h, l);
    hi[idx] = h;
    lo[idx] = l;
}

// ---------------------------------------------------------------------------
// GEMM1: C[M,256] = gelu(X[M,500] @ W1 + b1). Fused A-split (x read once),
// B pre-split planes [256,512] async-staged. 64x256 tile, BK=32, 4 waves 2x2.
// ---------------------------------------------------------------------------
#define GBM 64
#define GBN 256
#define GBK 32

__global__ __launch_bounds__(256) void gemm1_fused_kernel(
    const float* __restrict__ X,
    const short* __restrict__ Bhi, const short* __restrict__ Blo,
    const float* __restrict__ bias, float* __restrict__ C, int M)
{
    __shared__ short As[2][GBM * GBK];   // 8 KB
    __shared__ short Bs[2][GBN * GBK];   // 32 KB

    const int tid  = threadIdx.x;
    const int wid  = tid >> 6, lane = tid & 63;
    const int wm   = wid >> 1, wn = wid & 1;
    const int fm   = lane & 15, fq = lane >> 4;
    const int row0 = blockIdx.x * GBM;

    const int ar   = tid >> 2;          // staged A row 0..63
    const int aseg = tid & 3;           // 8-float segment
    const int gr   = min(row0 + ar, M - 1);

    f32x4 acc[2][8] = {};

    for (int ks = 0; ks < K1PAD / GBK; ks++) {
        const int k0 = ks * GBK;
        __syncthreads();   // previous iter's ds_reads done before overwrite

        // B staging (async global->LDS, 16B)
        #pragma unroll
        for (int i = 0; i < 4; i++) {
            const int c  = i * 256 + tid;
            const int n  = c >> 2, k8 = (c & 3) * 8;
            const int cb = (i * 256 + wid * 64) * 8;
            const size_t oB = (size_t)n * K1PAD + k0 + k8;
            async_load16(Bhi + oB, &Bs[0][cb]);
            async_load16(Blo + oB, &Bs[1][cb]);
        }
        // A staging: load x fp32, split -> hi/lo, ds_write
        {
            const int kb = k0 + aseg * 8;
            float v[8];
            if (k0 + GBK <= IN_C) {
                const float4 v0 = *(const float4*)(X + (size_t)gr * IN_C + kb);
                const float4 v1 = *(const float4*)(X + (size_t)gr * IN_C + kb + 4);
                v[0]=v0.x; v[1]=v0.y; v[2]=v0.z; v[3]=v0.w;
                v[4]=v1.x; v[5]=v1.y; v[6]=v1.z; v[7]=v1.w;
            } else {
                #pragma unroll
                for (int j = 0; j < 8; j++)
                    v[j] = (kb + j < IN_C) ? X[(size_t)gr * IN_C + kb + j] : 0.0f;
            }
            bf16x8 h8, l8;
            #pragma unroll
            for (int j = 0; j < 8; j++) { short th, tl; split2(v[j], th, tl); h8[j] = th; l8[j] = tl; }
            *(bf16x8*)&As[0][ar * GBK + aseg * 8] = h8;
            *(bf16x8*)&As[1][ar * GBK + aseg * 8] = l8;
        }
        __syncthreads();   // drains vmcnt + lgkmcnt: tiles ready

        bf16x8 ah[2], al[2];
        #pragma unroll
        for (int tm = 0; tm < 2; tm++) {
            const int r = wm * 32 + tm * 16 + fm;
            ah[tm] = *(const bf16x8*)&As[0][r * GBK + fq * 8];
            al[tm] = *(const bf16x8*)&As[1][r * GBK + fq * 8];
        }
        #pragma unroll
        for (int tn = 0; tn < 8; tn++) {
            const int cc = wn * 128 + tn * 16 + fm;
            const bf16x8 bh = *(const bf16x8*)&Bs[0][cc * GBK + fq * 8];
            const bf16x8 bl = *(const bf16x8*)&Bs[1][cc * GBK + fq * 8];
            #pragma unroll
            for (int tm = 0; tm < 2; tm++) {
                acc[tm][tn] = __builtin_amdgcn_mfma_f32_16x16x32_bf16(ah[tm], bh, acc[tm][tn], 0, 0, 0);
                acc[tm][tn] = __builtin_amdgcn_mfma_f32_16x16x32_bf16(ah[tm], bl, acc[tm][tn], 0, 0, 0);
                acc[tm][tn] = __builtin_amdgcn_mfma_f32_16x16x32_bf16(al[tm], bh, acc[tm][tn], 0, 0, 0);
            }
        }
    }

    // epilogue: C/D layout col=lane&15, row=fq*4+r
    #pragma unroll
    for (int tm = 0; tm < 2; tm++) {
        #pragma unroll
        for (int tn = 0; tn < 8; tn++) {
            const int gc = wn * 128 + tn * 16 + fm;
            const float bv = bias[gc];
            #pragma unroll
            for (int r = 0; r < 4; r++) {
                const int gr2 = row0 + wm * 32 + tm * 16 + fq * 4 + r;
                if (gr2 < M) {
                    float v = acc[tm][tn][r] + bv;
                    v = 0.5f * v * (1.0f + erff(v * 0.70710678118654752f));
                    C[(size_t)gr2 * 256 + gc] = v;
                }
            }
        }
    }
}

// ---------------------------------------------------------------------------
// GEMM2: C[M,256] = gelu(A[M,256] @ W2 + b2). A pre-split planes (from LN),
// B pre-split planes [256,256]. Same geometry, all async staging.
// ---------------------------------------------------------------------------
__global__ __launch_bounds__(256) void gemm2_kernel(
    const short* __restrict__ Ahi, const short* __restrict__ Alo,
    const short* __restrict__ Bhi, const short* __restrict__ Blo,
    const float* __restrict__ bias, float* __restrict__ C, int M)
{
    __shared__ short As[2][GBM * GBK];
    __shared__ short Bs[2][GBN * GBK];

    const int tid  = threadIdx.x;
    const int wid  = tid >> 6, lane = tid & 63;
    const int wm   = wid >> 1, wn = wid & 1;
    const int fm   = lane & 15, fq = lane >> 4;
    const int row0 = blockIdx.x * GBM;

    f32x4 acc[2][8] = {};

    for (int ks = 0; ks < K2PAD / GBK; ks++) {
        const int k0 = ks * GBK;
        __syncthreads();

        #pragma unroll
        for (int i = 0; i < 4; i++) {
            const int c  = i * 256 + tid;
            const int n  = c >> 2, k8 = (c & 3) * 8;
            const int cb = (i * 256 + wid * 64) * 8;
            const size_t oB = (size_t)n * K2PAD + k0 + k8;
            async_load16(Bhi + oB, &Bs[0][cb]);
            async_load16(Blo + oB, &Bs[1][cb]);
        }
        {
            const int m  = tid >> 2, k8 = (tid & 3) * 8;
            const int cb = (wid * 64) * 8;
            const size_t oA = (size_t)min(row0 + m, M - 1) * K2PAD + k0 + k8;
            async_load16(Ahi + oA, &As[0][cb]);
            async_load16(Alo + oA, &As[1][cb]);
        }
        __syncthreads();

        bf16x8 ah[2], al[2];
        #pragma unroll
        for (int tm = 0; tm < 2; tm++) {
            const int r = wm * 32 + tm * 16 + fm;
            ah[tm] = *(const bf16x8*)&As[0][r * GBK + fq * 8];
            al[tm] = *(const bf16x8*)&As[1][r * GBK + fq * 8];
        }
        #pragma unroll
        for (int tn = 0; tn < 8; tn++) {
            const int cc = wn * 128 + tn * 16 + fm;
            const bf16x8 bh = *(const bf16x8*)&Bs[0][cc * GBK + fq * 8];
            const bf16x8 bl = *(const bf16x8*)&Bs[1][cc * GBK + fq * 8];
            #pragma unroll
            for (int tm = 0; tm < 2; tm++) {
                acc[tm][tn] = __builtin_amdgcn_mfma_f32_16x16x32_bf16(ah[tm], bh, acc[tm][tn], 0, 0, 0);
                acc[tm][tn] = __builtin_amdgcn_mfma_f32_16x16x32_bf16(ah[tm], bl, acc[tm][tn], 0, 0, 0);
                acc[tm][tn] = __builtin_amdgcn_mfma_f32_16x16x32_bf16(al[tm], bh, acc[tm][tn], 0, 0, 0);
            }
        }
    }

    #pragma unroll
    for (int tm = 0; tm < 2; tm++) {
        #pragma unroll
        for (int tn = 0; tn < 8; tn++) {
            const int gc = wn * 128 + tn * 16 + fm;
            const float bv = bias[gc];
            #pragma unroll
            for (int r = 0; r < 4; r++) {
                const int gr2 = row0 + wm * 32 + tm * 16 + fq * 4 + r;
                if (gr2 < M) {
                    float v = acc[tm][tn][r] + bv;
                    v = 0.5f * v * (1.0f + erff(v * 0.70710678118654752f));
                    C[(size_t)gr2 * 256 + gc] = v;
                }
            }
        }
    }
}

// ---------------------------------------------------------------------------
// LayerNorm(256) -> bf16 hi/lo planes [M,256] (feeds GEMM2)
// ---------------------------------------------------------------------------
__global__ __launch_bounds__(256) void layernorm_split_kernel(
    const float* __restrict__ h, const float* __restrict__ g, const float* __restrict__ b,
    short* __restrict__ hi, short* __restrict__ lo, int nrows)
{
    const int wave = threadIdx.x >> 6;
    const int lane = threadIdx.x & 63;
    const int row  = blockIdx.x * 4 + wave;
    if (row >= nrows) return;

    const float* p = h + (size_t)row * HID;
    float v[4];
    float s = 0.0f;
    #pragma unroll
    for (int j = 0; j < 4; j++) { v[j] = p[lane + 64 * j]; s += v[j]; }
    #pragma unroll
    for (int off = 32; off > 0; off >>= 1) s += __shfl_xor(s, off);
    const float mu = s * (1.0f / 256.0f);

    float vs = 0.0f;
    #pragma unroll
    for (int j = 0; j < 4; j++) { float d = v[j] - mu; vs += d * d; }
    #pragma unroll
    for (int off = 32; off > 0; off >>= 1) vs += __shfl_xor(vs, off);
    const float rs = rsqrtf(vs * (1.0f / 256.0f) + LN_EPS);

    #pragma unroll
    for (int j = 0; j < 4; j++) {
        const int c = lane + 64 * j;
        const float o = (v[j] - mu) * rs * g[c] + b[c];
        short th, tl;
        split2(o, th, tl);
        hi[(size_t)row * HID + c] = th;
        lo[(size_t)row * HID + c] = tl;
    }
}

// plain fp32 in-place LayerNorm (before gemm3)
__global__ __launch_bounds__(256) void layernorm_kernel(
    float* __restrict__ h, const float* __restrict__ g, const float* __restrict__ b, int nrows)
{
    const int wave = threadIdx.x >> 6;
    const int lane = threadIdx.x & 63;
    const int row  = blockIdx.x * 4 + wave;
    if (row >= nrows) return;

    float* p = h + (size_t)row * HID;
    float v[4];
    float s = 0.0f;
    #pragma unroll
    for (int j = 0; j < 4; j++) { v[j] = p[lane + 64 * j]; s += v[j]; }
    #pragma unroll
    for (int off = 32; off > 0; off >>= 1) s += __shfl_xor(s, off);
    const float mu = s * (1.0f / 256.0f);

    float vs = 0.0f;
    #pragma unroll
    for (int j = 0; j < 4; j++) { float d = v[j] - mu; vs += d * d; }
    #pragma unroll
    for (int off = 32; off > 0; off >>= 1) vs += __shfl_xor(vs, off);
    const float rs = rsqrtf(vs * (1.0f / 256.0f) + LN_EPS);

    #pragma unroll
    for (int j = 0; j < 4; j++) {
        int c = lane + 64 * j;
        p[c] = (v[j] - mu) * rs * g[c] + b[c];
    }
}

// ---------------------------------------------------------------------------
// GEMM3: [N,256] @ [256,40] + b3, W3 staged in LDS (40 KB)
// ---------------------------------------------------------------------------
__global__ __launch_bounds__(256) void gemm3_kernel(
    const float* __restrict__ A, const float* __restrict__ W,
    const float* __restrict__ bias, float* __restrict__ C, int M)
{
    __shared__ float Ws[HID * OUT_C];
    __shared__ float bs[OUT_C];
    for (int i = threadIdx.x; i < HID * OUT_C; i += 256) Ws[i] = W[i];
    if (threadIdx.x < OUT_C) bs[threadIdx.x] = bias[threadIdx.x];
    __syncthreads();

    const int total = M * OUT_C;
    for (int idx = blockIdx.x * 256 + threadIdx.x; idx < total; idx += gridDim.x * 256) {
        const int r = idx / OUT_C;
        const int c = idx - r * OUT_C;
        const float4* a4 = reinterpret_cast<const float4*>(A + (size_t)r * HID);
        float s = 0.0f;
        #pragma unroll 4
        for (int k4 = 0; k4 < HID / 4; k4++) {
            float4 av = a4[k4];
            const float* wp = &Ws[k4 * 4 * OUT_C + c];
            s += av.x * wp[0] + av.y * wp[OUT_C] + av.z * wp[2 * OUT_C] + av.w * wp[3 * OUT_C];
        }
        C[idx] = s + bs[c];
    }
}

// ---------------------------------------------------------------------------
// APPNP step: one wave per node; lane = (edge-group g=lane/10, quad q=lane%10).
// 6 edges per gather instruction (float4 per lane), shuffle reduce over g.
// ---------------------------------------------------------------------------
__global__ __launch_bounds__(256) void appnp_kernel(
    const int* __restrict__ offs, const int2* __restrict__ csr_ew,
    const float* __restrict__ dinv,
    const float* __restrict__ h, const float* __restrict__ h0,
    float* __restrict__ out)
{
    const int node = blockIdx.x * 4 + (threadIdx.x >> 6);
    if (node >= N_NODES) return;           // wave-uniform exit
    const int lane = threadIdx.x & 63;
    const int g = lane / 10;               // 0..6 (g==6 => lanes 60..63 idle)
    const int q = lane - g * 10;           // channel quad 0..9
    const bool act = (lane < 60);

    const int start = offs[node];
    const int end   = offs[node + 1];

    float ax = 0.0f, ay = 0.0f, az = 0.0f, aw = 0.0f;
    for (int e0 = start; e0 < end; e0 += 6) {
        const int  ee = e0 + g;
        const bool ea = act && (ee < end);
        const int2 ed = csr_ew[ea ? ee : start];
        const float w = ea ? __int_as_float(ed.y) : 0.0f;
        const float4 hv = *(const float4*)(h + (size_t)ed.x * OUT_C + q * 4);
        ax += w * hv.x; ay += w * hv.y; az += w * hv.z; aw += w * hv.w;
    }

    // reduce over edge-groups: lanes {q, q+10, ..., q+50} -> lane q
    ax += __shfl(ax, lane + 30); ay += __shfl(ay, lane + 30);
    az += __shfl(az, lane + 30); aw += __shfl(aw, lane + 30);
    {
        const float bx = __shfl(ax, lane + 10), cx = __shfl(ax, lane + 20);
        const float by = __shfl(ay, lane + 10), cy = __shfl(ay, lane + 20);
        const float bz = __shfl(az, lane + 10), cz = __shfl(az, lane + 20);
        const float bw = __shfl(aw, lane + 10), cw = __shfl(aw, lane + 20);
        ax += bx + cx; ay += by + cy; az += bz + cz; aw += bw + cw;
    }

    if (lane < 10) {
        const float d = dinv[node];
        const float self = d * d;
        const size_t idx = (size_t)node * OUT_C + lane * 4;
        const float4 hs  = *(const float4*)(h + idx);
        const float4 h0v = *(const float4*)(h0 + idx);
        float4 o;
        o.x = (1.0f - ALPHA) * (ax + self * hs.x) + ALPHA * h0v.x;
        o.y = (1.0f - ALPHA) * (ay + self * hs.y) + ALPHA * h0v.y;
        o.z = (1.0f - ALPHA) * (az + self * hs.z) + ALPHA * h0v.z;
        o.w = (1.0f - ALPHA) * (aw + self * hs.w) + ALPHA * h0v.w;
        *(float4*)(out + idx) = o;
    }
}

// ---------------------------------------------------------------------------
extern "C" void kernel_launch(void* const* d_in, const int* in_sizes, int n_in,
                              void* d_out, int out_size, void* d_ws, size_t ws_size,
                              hipStream_t stream) {
    const float* x   = (const float*)d_in[0];
    const int*   ei  = (const int*)d_in[1];
    const float* W1  = (const float*)d_in[2];
    const float* b1  = (const float*)d_in[3];
    const float* g1  = (const float*)d_in[4];
    const float* be1 = (const float*)d_in[5];
    const float* W2  = (const float*)d_in[6];
    const float* b2  = (const float*)d_in[7];
    const float* g2  = (const float*)d_in[8];
    const float* be2 = (const float*)d_in[9];
    const float* W3  = (const float*)d_in[10];
    const float* b3  = (const float*)d_in[11];
    float* out = (float*)d_out;

    const int* e_row = ei;
    const int* e_col = ei + N_EDGES;

    // ---- workspace layout (float units), regions aliased by liveness ----
    float* ws = (float*)d_ws;
    size_t off = 0;
    float* dinv = ws + off; off += N_NODES;
    int*   cnt  = (int*)(ws + off); off += N_NODES;
    int*   offs = (int*)(ws + off); off += N_NODES + 1;
    int*   bsum = (int*)(ws + off); off += 128 + 3;      // +3: keep 16B alignment downstream
    short* W1hi = (short*)(ws + off); off += 65536;      // 256*512 shorts
    short* W1lo = (short*)(ws + off); off += 65536;
    short* W2hi = (short*)(ws + off); off += 32768;      // 256*256 shorts
    short* W2lo = (short*)(ws + off); off += 32768;
    // Region B: t1 (GEMM1 out) -> t2 (GEMM2 out, aliased)
    float* t1 = ws + off; off += (size_t)N_NODES * HID;
    float* t2 = t1;
    // Region A: A2 planes (25.6M floats) -> csr_ew + h0/hA/hB (15.2M floats)
    float* regA = ws + off; off += (size_t)N_NODES * HID;
    short* A2hi = (short*)regA;
    short* A2lo = A2hi + (size_t)N_NODES * HID;
    int2*  csr_ew = (int2*)regA;                         // 1.6M int2 = 3.2M floats
    float* h0 = regA + 2 * (size_t)N_EDGES;
    float* hA = h0 + (size_t)N_NODES * OUT_C;
    float* hB = hA + (size_t)N_NODES * OUT_C;

    // --- degree / dinv / offsets ---
    hipMemsetAsync(cnt, 0, N_NODES * sizeof(int), stream);
    deg_count_kernel<<<(N_EDGES + 255) / 256, 256, 0, stream>>>(e_col, cnt, N_EDGES);
    dinv_kernel<<<(N_NODES + 255) / 256, 256, 0, stream>>>(cnt, dinv, N_NODES);
    scan_partial_kernel<<<NBLK_SCAN, 256, 0, stream>>>(cnt, bsum);
    scan_bsum_kernel<<<1, 128, 0, stream>>>(bsum, NBLK_SCAN);
    scan_final_kernel<<<NBLK_SCAN, 256, 0, stream>>>(cnt, bsum, offs);
    set_total_kernel<<<1, 64, 0, stream>>>(offs);

    // --- weight pre-split ---
    wsplit_kernel<<<(256 * K1PAD + 255) / 256, 256, 0, stream>>>(W1, W1hi, W1lo, IN_C, 256, K1PAD);
    wsplit_kernel<<<(256 * K2PAD + 255) / 256, 256, 0, stream>>>(W2, W2hi, W2lo, HID, 256, K2PAD);

    // --- MLP ---
    {
        const int nblk = (N_NODES + GBM - 1) / GBM;   // 1563
        gemm1_fused_kernel<<<nblk, 256, 0, stream>>>(x, W1hi, W1lo, b1, t1, N_NODES);
        layernorm_split_kernel<<<(N_NODES + 3) / 4, 256, 0, stream>>>(t1, g1, be1, A2hi, A2lo, N_NODES);
        gemm2_kernel<<<nblk, 256, 0, stream>>>(A2hi, A2lo, W2hi, W2lo, b2, t2, N_NODES);
        layernorm_kernel<<<(N_NODES + 3) / 4, 256, 0, stream>>>(t2, g2, be2, N_NODES);
        gemm3_kernel<<<2048, 256, 0, stream>>>(t2, W3, b3, h0, N_NODES);
    }

    // --- CSR build (A2 planes dead; cnt reused as fill cursor) ---
    hipMemsetAsync(cnt, 0, N_NODES * sizeof(int), stream);
    csr_fill_kernel<<<(N_EDGES + 255) / 256, 256, 0, stream>>>(
        e_row, e_col, dinv, offs, cnt, csr_ew, N_EDGES);

    // --- APPNP: 10 gather steps ---
    const float* hcur = h0;
    for (int it = 0; it < K_ITERS; it++) {
        float* tgt = (it == K_ITERS - 1) ? out : ((it & 1) ? hB : hA);
        appnp_kernel<<<(N_NODES + 3) / 4, 256, 0, stream>>>(
            offs, csr_ew, dinv, hcur, h0, tgt);
        hcur = tgt;
    }
}